// Round 7
// baseline (561.486 us; speedup 1.0000x reference)
//
#include <hip/hip_runtime.h>
#include <cfloat>

// VectorQuantizer: N=32768 rows, K=8192 codes, D=256, fp32.
// R2/R3 (absmax 0): reference = numpy fp32; d_k = fl32(fl32(x2+wn_k)-fl32(2*m_k)),
// m_k = single fp32 FMA chain d-ascending; first-occurrence argmin. Exact top-8
// rescore of approximate-scorer candidates reproduces it bit-for-bit.
// R6 (125.3us score): 64-row blocks, LDS dbuf + syncthreads.      MfmaUtil 22.5
// R10 (119.4us): barrier-free counted-vmcnt pipeline.             MfmaUtil 24
// R12 (117.7us): + deferred SEL + B reg-prefetch.                 MfmaUtil 24.5
//   Three schedules, same wall => NOT schedule-bound. Arithmetic: wall 4414
//   cy/SIMD/kt-pair vs 1100 cy matrix demand (=25%=MfmaUtil) + ~700 real VALU;
//   ~2600 cy both-waves-stalled. 2 phase-identical waves/SIMD (Occ 18%) can't
//   cover each other's dep-chain + operand latencies => LATENCY-BOUND, TLP-LIMITED.
// R13 (this round): TLP 2->3 waves/SIMD + delete the LDS round-trip.
//   - R10 proved no cross-wave data flow: staging W through LDS was never
//     needed. B-fragments now loaded DIRECTLY global->VGPR (wb8 = 2MB,
//     L2-resident; strided reads absorbed by L2 at 25% util).
//   - 32-row blocks (af 32, acc 16, s0/s1 32 regs), grid 1024, LDS = 32KB
//     merge only, launch_bounds(256,3): 12 waves/CU (LDS 96KB/CU, VGPR<=170).
//   - B double-buffered at kt granularity (64 regs), issued a full iteration
//     (~1500cy) ahead of use -> L2 latency covered.
//   - candidate set BIT-IDENTICAL to R6/R10 by construction: per row, slot =
//     code mod 128 (via wave,lane), top-2/slot, 256 keys/row, same ks-order
//     acc chain, same key build/merge/top-8; rescore unchanged.
//   - no barriers, no inline asm, no vmcnt bookkeeping left in the K-loop.
// prep_w / rescore untouched (bit-exact verified).

#define DDIM 256

typedef int   i32x8  __attribute__((ext_vector_type(8)));
typedef float f32x16 __attribute__((ext_vector_type(16)));

// ---------- W prep: numpy-exact ||w||^2 + negated scaled fp8 ----------
__global__ __launch_bounds__(256) void vq_prep_w(
    const float* __restrict__ w, float* __restrict__ wn,
    unsigned char* __restrict__ wb8) {
    __shared__ float rows[32 * 260];
    const int tid = threadIdx.x;
    const int r0 = blockIdx.x * 32;

    for (int idx = tid; idx < 32 * 64; idx += 256) {
        int r = idx >> 6, c4 = idx & 63;
        *(float4*)&rows[r * 260 + c4 * 4] =
            *(const float4*)(w + (size_t)(r0 + r) * DDIM + c4 * 4);
    }
    __syncthreads();
    {
        // numpy pairwise_sum(fl(a*a),256): two 128-halves, each 8 stride-8
        // chains, ((r0+r1)+(r2+r3))+((r4+r5)+(r6+r7)); shfl-xor == nesting.
        const int row = (tid >> 6) * 8 + ((tid & 63) >> 3), j = tid & 7;
        const float* a = &rows[row * 260];
        float half[2];
#pragma unroll
        for (int h = 0; h < 2; ++h) {
            const float* b = a + h * 128 + j;
            float r = __fmul_rn(b[0], b[0]);
#pragma unroll
            for (int t = 1; t < 16; ++t)
                r = __fadd_rn(r, __fmul_rn(b[8 * t], b[8 * t]));
            float p = __fadd_rn(r, __shfl_xor(r, 1, 64));
            p = __fadd_rn(p, __shfl_xor(p, 2, 64));
            p = __fadd_rn(p, __shfl_xor(p, 4, 64));
            half[h] = p;
        }
        if (j == 0) wn[r0 + row] = __fadd_rn(half[0], half[1]);
    }
    // fp8 e4m3 emission, scaled by -2^13 (pow2 cancels in argmin; negation
    // folds the "-2m" sign so acc = C - m_s with C=128 init)
    for (int idx = tid; idx < 32 * 16; idx += 256) {
        int r = idx >> 4, s = idx & 15;
        const float* p = &rows[r * 260 + s * 16];
        unsigned q[4];
#pragma unroll
        for (int m = 0; m < 4; ++m) {
            unsigned v = (unsigned)__builtin_amdgcn_cvt_pk_fp8_f32(
                p[m * 4 + 0] * -8192.f, p[m * 4 + 1] * -8192.f, 0, false);
            v = (unsigned)__builtin_amdgcn_cvt_pk_fp8_f32(
                p[m * 4 + 2] * -8192.f, p[m * 4 + 3] * -8192.f, (int)v, true);
            q[m] = v;
        }
        *(uint4*)(wb8 + (size_t)(r0 + r) * DDIM + s * 16) =
            make_uint4(q[0], q[1], q[2], q[3]);
    }
}

// ---------- MX-fp8 scorer: 32 rows x 8192 cols per block, 3 blocks/CU ----------
// 256 thr = 4 waves (wave = 32-col group); per wave per kt: 1 MFMA chain of 4
// (ks over D=256). A and B both resident in VGPRs; B loaded direct from global
// (L2-hot), kt-level register double-buffer. No LDS staging, no barriers in
// the K-loop. LDS = 32KB merge buffer only.
// C/D (32x32): col=lane&31, row=(reg&3)+8*(reg>>2)+4*(lane>>5)  [m74/m101].

#define INIT128(C) { _Pragma("unroll") for (int r_ = 0; r_ < 16; ++r_) (C)[r_] = 128.0f; }

// selection (R6-verbatim logic, single set): acc = 128 - m_s > 0, uint-
// monotone; top-2 per (lane,reg) slot = code residue mod 128 per row.
#define SEL16(P, pkt) { \
    const unsigned colv_ = (unsigned)((pkt) * 128 + bcol); \
    _Pragma("unroll") for (int r_ = 0; r_ < 16; ++r_) { \
        unsigned key_ = (__float_as_uint((P)[r_]) & 0xFFFFE000u) | colv_; \
        unsigned a0_ = s0[r_]; \
        unsigned mx_ = key_ > a0_ ? key_ : a0_; \
        s1[r_] = mx_ < s1[r_] ? mx_ : s1[r_]; \
        s0[r_] = key_ < a0_ ? key_ : a0_; \
    } }

// direct global->reg B-fragment load for tile kt (8 x dwordx4, 256B stride)
#define LOADB(dst, kt) { \
    _Pragma("unroll") for (int ks_ = 0; ks_ < 4; ++ks_) { \
        dst[ks_].q[0] = *(const uint4*)(wB + (kt) * 32768 + ks_ * 64); \
        dst[ks_].q[1] = *(const uint4*)(wB + (kt) * 32768 + ks_ * 64 + 16); \
    } }

#define MFMA4(B) do { \
    __builtin_amdgcn_s_setprio(1); \
    acc = __builtin_amdgcn_mfma_scale_f32_32x32x64_f8f6f4( \
        af[0], B[0].v, acc, 0, 0, 0, 0x7F7F7F7F, 0, 0x7F7F7F7F); \
    acc = __builtin_amdgcn_mfma_scale_f32_32x32x64_f8f6f4( \
        af[1], B[1].v, acc, 0, 0, 0, 0x7F7F7F7F, 0, 0x7F7F7F7F); \
    acc = __builtin_amdgcn_mfma_scale_f32_32x32x64_f8f6f4( \
        af[2], B[2].v, acc, 0, 0, 0, 0x7F7F7F7F, 0, 0x7F7F7F7F); \
    acc = __builtin_amdgcn_mfma_scale_f32_32x32x64_f8f6f4( \
        af[3], B[3].v, acc, 0, 0, 0, 0x7F7F7F7F, 0, 0x7F7F7F7F); \
    __builtin_amdgcn_s_setprio(0); \
  } while (0)

__global__ __launch_bounds__(256, 3) void vq_score(
    const float* __restrict__ x, const unsigned char* __restrict__ wb8,
    unsigned* __restrict__ cand) {
    __shared__ unsigned ms[32 * 256];   // 32 KB merge buffer
    const int tid = threadIdx.x;
    const int wave = tid >> 6, lane = tid & 63;
    const int h = lane >> 5, c32 = lane & 31;
    const int rowBase = blockIdx.x * 32;
    const int bcol = wave * 32 + c32;

    // A fragments: 32 rows x 256 dims fp8 (row = c32), converted in-kernel.
    // Lane layout for MFMA A: row = lane&31, k = ks*64 + (lane>>5)*32 + j.
    i32x8 af[4];
    {
        const float* xr = x + (size_t)(rowBase + c32) * DDIM;
#pragma unroll
        for (int ks = 0; ks < 4; ++ks) {
            const float4* p = (const float4*)(xr + ks * 64 + h * 32);
            union { int d[8]; i32x8 v; } u;
#pragma unroll
            for (int m = 0; m < 8; ++m) {
                float4 f = p[m];
                unsigned v = (unsigned)__builtin_amdgcn_cvt_pk_fp8_f32(
                    f.x, f.y, 0, false);
                v = (unsigned)__builtin_amdgcn_cvt_pk_fp8_f32(
                    f.z, f.w, (int)v, true);
                u.d[m] = (int)v;
            }
            af[ks] = u.v;
        }
    }

    // B lane base: code bcol, dims h*32; per (kt,ks): +kt*32768 + ks*64.
    const unsigned char* wB = wb8 + (size_t)bcol * 256 + h * 32;

    unsigned s0[16], s1[16];
#pragma unroll
    for (int r = 0; r < 16; ++r) { s0[r] = 0xFFFFFFFFu; s1[r] = 0xFFFFFFFFu; }

    f32x16 acc;
    union Bu { uint4 q[2]; i32x8 v; };
    Bu bE[4], bO[4];

    // kt-level register double-buffer: loads for kt+1 issued before computing
    // kt -> a full iteration of MFMA+SEL (~1.5k cy) hides L2 latency.
    LOADB(bE, 0);
    for (int kt = 0; kt < 64; kt += 2) {
        LOADB(bO, kt + 1);
        INIT128(acc);
        MFMA4(bE);
        SEL16(acc, kt);
        if (kt + 2 < 64) LOADB(bE, kt + 2);
        INIT128(acc);
        MFMA4(bO);
        SEL16(acc, kt + 1);
    }

    // merge: 32 rows x 256 keys = 32 KB; per-thread writes disjoint
    for (int r = 0; r < 16; ++r) {
        int rloc = (r & 3) + 8 * (r >> 2) + 4 * h;
        *(uint2*)&ms[rloc * 256 + bcol * 2] = make_uint2(s0[r], s1[r]);
    }
    __syncthreads();
    if (tid < 32) {
        const uint4* rowk = (const uint4*)(ms + tid * 256);
        unsigned best[8];
#pragma unroll
        for (int i = 0; i < 8; ++i) best[i] = 0xFFFFFFFFu;
        for (int i = 0; i < 64; ++i) {
            uint4 qv = rowk[(i + tid) & 63];   // rotated: bank spread
            unsigned kk[4] = {qv.x, qv.y, qv.z, qv.w};
#pragma unroll
            for (int e = 0; e < 4; ++e) {
                unsigned key = kk[e];
                if (key < best[7]) {
                    best[7] = key;
#pragma unroll
                    for (int j = 7; j > 0; --j)
                        if (best[j] < best[j - 1]) {
                            unsigned t = best[j]; best[j] = best[j - 1]; best[j - 1] = t;
                        }
                }
            }
        }
        unsigned* out = cand + (size_t)(rowBase + tid) * 8;
#pragma unroll
        for (int i = 0; i < 8; ++i) out[i] = best[i];
    }
}

// ---------- exact rescore (fp32 chain, R3-verified) + inline numpy x2 ----------
__global__ __launch_bounds__(256) void vq_rescore_write(
    const float* __restrict__ x, const float* __restrict__ w,
    const float* __restrict__ wn, const unsigned* __restrict__ cand,
    float* __restrict__ outq, float* __restrict__ outi) {
    __shared__ int winners[32];
    const int tid = threadIdx.x;
    const int lr = tid >> 3, cc = tid & 7;
    const int row = blockIdx.x * 32 + lr;

    int k = (int)(cand[(size_t)row * 8 + cc] & 0x1FFFu);
    const float* xr = x + (size_t)row * DDIM;
    const float* wr = w + (size_t)k * DDIM;
    // dot: single fp32 fmaf chain d-ascending (BLAS-exact, R2/R3-verified)
    // x2: numpy pairwise (two halves, 8 stride-8 chains, exact nesting)
    float dot = 0.f;
    float half[2];
#pragma unroll
    for (int hh = 0; hh < 2; ++hh) {
        float r[8];
#pragma unroll
        for (int t = 0; t < 16; ++t) {
            const int d = hh * 128 + t * 8;
            float4 xa = *(const float4*)(xr + d);
            float4 xb = *(const float4*)(xr + d + 4);
            float4 wa = *(const float4*)(wr + d);
            float4 wb = *(const float4*)(wr + d + 4);
            dot = __fmaf_rn(xa.x, wa.x, dot); dot = __fmaf_rn(xa.y, wa.y, dot);
            dot = __fmaf_rn(xa.z, wa.z, dot); dot = __fmaf_rn(xa.w, wa.w, dot);
            dot = __fmaf_rn(xb.x, wb.x, dot); dot = __fmaf_rn(xb.y, wb.y, dot);
            dot = __fmaf_rn(xb.z, wb.z, dot); dot = __fmaf_rn(xb.w, wb.w, dot);
            if (t == 0) {
                r[0] = __fmul_rn(xa.x, xa.x); r[1] = __fmul_rn(xa.y, xa.y);
                r[2] = __fmul_rn(xa.z, xa.z); r[3] = __fmul_rn(xa.w, xa.w);
                r[4] = __fmul_rn(xb.x, xb.x); r[5] = __fmul_rn(xb.y, xb.y);
                r[6] = __fmul_rn(xb.z, xb.z); r[7] = __fmul_rn(xb.w, xb.w);
            } else {
                r[0] = __fadd_rn(r[0], __fmul_rn(xa.x, xa.x));
                r[1] = __fadd_rn(r[1], __fmul_rn(xa.y, xa.y));
                r[2] = __fadd_rn(r[2], __fmul_rn(xa.z, xa.z));
                r[3] = __fadd_rn(r[3], __fmul_rn(xa.w, xa.w));
                r[4] = __fadd_rn(r[4], __fmul_rn(xb.x, xb.x));
                r[5] = __fadd_rn(r[5], __fmul_rn(xb.y, xb.y));
                r[6] = __fadd_rn(r[6], __fmul_rn(xb.w == xb.w ? xb.z : xb.z, xb.z));
                r[7] = __fadd_rn(r[7], __fmul_rn(xb.w, xb.w));
            }
        }
        half[hh] = __fadd_rn(__fadd_rn(__fadd_rn(r[0], r[1]), __fadd_rn(r[2], r[3])),
                             __fadd_rn(__fadd_rn(r[4], r[5]), __fadd_rn(r[6], r[7])));
    }
    float x2v = __fadd_rn(half[0], half[1]);
    float dv = __fsub_rn(__fadd_rn(x2v, wn[k]), __fmul_rn(2.0f, dot));
    // lexicographic (dv,k) min across 8 candidate lanes (first-occurrence)
#pragma unroll
    for (int m = 1; m < 8; m <<= 1) {
        float od = __shfl_xor(dv, m, 64);
        int   ok = __shfl_xor(k,  m, 64);
        if (od < dv || (od == dv && ok < k)) { dv = od; k = ok; }
    }
    if (cc == 0) winners[lr] = k;
    __syncthreads();
    if (tid < 32) outi[blockIdx.x * 32 + tid] = (float)winners[tid];
    for (int u = tid; u < 32 * 64; u += 256) {
        int r = u >> 6, c4 = u & 63;
        *reinterpret_cast<float4*>(outq + (size_t)(blockIdx.x * 32 + r) * DDIM + c4 * 4) =
            *reinterpret_cast<const float4*>(w + (size_t)winners[r] * DDIM + c4 * 4);
    }
}

extern "C" void kernel_launch(void* const* d_in, const int* in_sizes, int n_in,
                              void* d_out, int out_size, void* d_ws, size_t ws_size,
                              hipStream_t stream) {
    const float* x = (const float*)d_in[0];
    const float* w = (const float*)d_in[1];
    const int N = in_sizes[0] / DDIM;   // 32768
    const int K = in_sizes[1] / DDIM;   // 8192
    float* outq = (float*)d_out;
    float* outi = outq + (size_t)N * DDIM;

    unsigned char* wb8 = (unsigned char*)d_ws;                // K*256 = 2 MB
    float* wn = (float*)(wb8 + (size_t)K * DDIM);             // K floats
    unsigned* cand = (unsigned*)(wn + K);                     // N*8 u32 = 1 MB

    hipLaunchKernelGGL(vq_prep_w, dim3(K / 32), dim3(256), 0, stream, w, wn, wb8);
    hipLaunchKernelGGL(vq_score, dim3(N / 32), dim3(256), 0, stream, x, wb8, cand);
    hipLaunchKernelGGL(vq_rescore_write, dim3(N / 32), dim3(256), 0, stream,
                       x, w, wn, cand, outq, outi);
}

// Round 8
// 408.964 us; speedup vs baseline: 1.3729x; 1.3729x over previous
//
#include <hip/hip_runtime.h>
#include <cfloat>

// VectorQuantizer: N=32768 rows, K=8192 codes, D=256, fp32.
// R2/R3 (absmax 0): reference = numpy fp32; d_k = fl32(fl32(x2+wn_k)-fl32(2*m_k)),
// m_k = single fp32 FMA chain d-ascending; first-occurrence argmin. Exact top-8
// rescore of approximate-scorer candidates reproduces it bit-for-bit.
// R6 (125.3us score): 64-row LDS dbuf + syncthreads.               MfmaUtil 22.5
// R10 (119.4us): barrier-free counted-vmcnt pipeline.              MfmaUtil 24
// R12 (117.7us): + deferred SEL + B reg-prefetch.                  MfmaUtil 24.5
//   => latency-bound, TLP-limited: 2 phase-identical waves/SIMD leave ~55% of
//   SIMD cycles with both waves stalled (MFMA issue 25% + real VALU ~15%).
// R13 (447us REGRESSION, but absmax 0): no-LDS direct-L2 B, 32-row blocks,
//   grid 1024. __launch_bounds__(256,3) made the allocator clamp to VGPR=84
//   (=512/6!) -> total spill: WRITE_SIZE 600MB scratch, MfmaUtil 6%. The
//   STRUCTURE (candidate set, merge, direct-B) is now HW-verified correct;
//   only the register axis failed. 2nd launch_bounds arg = confirmed foot-gun.
// R14 (this round): R13 with the register axis fixed, one variable:
//   - plain __launch_bounds__(256) (no 2nd arg, no clamp). Occupancy follows
//     allocation: ~155-170 live regs -> 3 waves/SIMD (vs 2 in R6-R12). LDS is
//     only the 32KB merge buffer, so VGPR is the sole occupancy limiter.
//   - B prefetch split into two half-batches interleaved between the current
//     tile's MFMA pairs (bounds peak liveness, keeps ~340cy lead per chunk
//     over L2 latency). Same data, same MFMA/SEL order per kt => bit-identical
//     candidate set to the verified R13.
//   - OOB guard on the final prefetch (R13 read 32KB into wn; now skipped).
//   Tripwire: WRITE_SIZE must stay 1024KB exactly; VGPR 140-175 expected.
//   L2 floor: 1024 blocks x 2MB W = 2GB / 34.5TB/s ~ 58us.
// prep_w / rescore untouched (bit-exact verified).

#define DDIM 256

typedef int   i32x8  __attribute__((ext_vector_type(8)));
typedef float f32x16 __attribute__((ext_vector_type(16)));

// ---------- W prep: numpy-exact ||w||^2 + negated scaled fp8 ----------
__global__ __launch_bounds__(256) void vq_prep_w(
    const float* __restrict__ w, float* __restrict__ wn,
    unsigned char* __restrict__ wb8) {
    __shared__ float rows[32 * 260];
    const int tid = threadIdx.x;
    const int r0 = blockIdx.x * 32;

    for (int idx = tid; idx < 32 * 64; idx += 256) {
        int r = idx >> 6, c4 = idx & 63;
        *(float4*)&rows[r * 260 + c4 * 4] =
            *(const float4*)(w + (size_t)(r0 + r) * DDIM + c4 * 4);
    }
    __syncthreads();
    {
        // numpy pairwise_sum(fl(a*a),256): two 128-halves, each 8 stride-8
        // chains, ((r0+r1)+(r2+r3))+((r4+r5)+(r6+r7)); shfl-xor == nesting.
        const int row = (tid >> 6) * 8 + ((tid & 63) >> 3), j = tid & 7;
        const float* a = &rows[row * 260];
        float half[2];
#pragma unroll
        for (int h = 0; h < 2; ++h) {
            const float* b = a + h * 128 + j;
            float r = __fmul_rn(b[0], b[0]);
#pragma unroll
            for (int t = 1; t < 16; ++t)
                r = __fadd_rn(r, __fmul_rn(b[8 * t], b[8 * t]));
            float p = __fadd_rn(r, __shfl_xor(r, 1, 64));
            p = __fadd_rn(p, __shfl_xor(p, 2, 64));
            p = __fadd_rn(p, __shfl_xor(p, 4, 64));
            half[h] = p;
        }
        if (j == 0) wn[r0 + row] = __fadd_rn(half[0], half[1]);
    }
    // fp8 e4m3 emission, scaled by -2^13 (pow2 cancels in argmin; negation
    // folds the "-2m" sign so acc = C - m_s with C=128 init)
    for (int idx = tid; idx < 32 * 16; idx += 256) {
        int r = idx >> 4, s = idx & 15;
        const float* p = &rows[r * 260 + s * 16];
        unsigned q[4];
#pragma unroll
        for (int m = 0; m < 4; ++m) {
            unsigned v = (unsigned)__builtin_amdgcn_cvt_pk_fp8_f32(
                p[m * 4 + 0] * -8192.f, p[m * 4 + 1] * -8192.f, 0, false);
            v = (unsigned)__builtin_amdgcn_cvt_pk_fp8_f32(
                p[m * 4 + 2] * -8192.f, p[m * 4 + 3] * -8192.f, (int)v, true);
            q[m] = v;
        }
        *(uint4*)(wb8 + (size_t)(r0 + r) * DDIM + s * 16) =
            make_uint4(q[0], q[1], q[2], q[3]);
    }
}

// ---------- MX-fp8 scorer: 32 rows x 8192 cols per block ----------
// 256 thr = 4 waves (wave = 32-col group); per wave per kt: 1 MFMA chain of 4
// (ks over D=256). A and B both resident in VGPRs; B loaded direct from global
// (L2-hot), interleaved half-batch prefetch. No LDS staging, no barriers in
// the K-loop. LDS = 32KB merge buffer only. Occupancy = VGPR-limited.
// C/D (32x32): col=lane&31, row=(reg&3)+8*(reg>>2)+4*(lane>>5)  [m74/m101].

#define INIT128(C) { _Pragma("unroll") for (int r_ = 0; r_ < 16; ++r_) (C)[r_] = 128.0f; }

// selection (R6-verbatim logic): acc = 128 - m_s > 0, uint-monotone;
// top-2 per (lane,reg) slot = code residue mod 128 per row.
#define SEL16(P, pkt) { \
    const unsigned colv_ = (unsigned)((pkt) * 128 + bcol); \
    _Pragma("unroll") for (int r_ = 0; r_ < 16; ++r_) { \
        unsigned key_ = (__float_as_uint((P)[r_]) & 0xFFFFE000u) | colv_; \
        unsigned a0_ = s0[r_]; \
        unsigned mx_ = key_ > a0_ ? key_ : a0_; \
        s1[r_] = mx_ < s1[r_] ? mx_ : s1[r_]; \
        s0[r_] = key_ < a0_ ? key_ : a0_; \
    } }

// one B chunk (ks) of tile kt: 2 x dwordx4 at 256B-stride lane base
#define LOADC(dst, kt, ks) { \
    dst.q[0] = *(const uint4*)(wB + (kt) * 32768 + (ks) * 64); \
    dst.q[1] = *(const uint4*)(wB + (kt) * 32768 + (ks) * 64 + 16); }

#define MFMA1(A, B) \
    acc = __builtin_amdgcn_mfma_scale_f32_32x32x64_f8f6f4( \
        A, B.v, acc, 0, 0, 0, 0x7F7F7F7F, 0, 0x7F7F7F7F)

__global__ __launch_bounds__(256) void vq_score(
    const float* __restrict__ x, const unsigned char* __restrict__ wb8,
    unsigned* __restrict__ cand) {
    __shared__ unsigned ms[32 * 256];   // 32 KB merge buffer
    const int tid = threadIdx.x;
    const int wave = tid >> 6, lane = tid & 63;
    const int h = lane >> 5, c32 = lane & 31;
    const int rowBase = blockIdx.x * 32;
    const int bcol = wave * 32 + c32;

    // A fragments: 32 rows x 256 dims fp8 (row = c32), converted in-kernel.
    i32x8 af[4];
    {
        const float* xr = x + (size_t)(rowBase + c32) * DDIM;
#pragma unroll
        for (int ks = 0; ks < 4; ++ks) {
            const float4* p = (const float4*)(xr + ks * 64 + h * 32);
            union { int d[8]; i32x8 v; } u;
#pragma unroll
            for (int m = 0; m < 8; ++m) {
                float4 f = p[m];
                unsigned v = (unsigned)__builtin_amdgcn_cvt_pk_fp8_f32(
                    f.x, f.y, 0, false);
                v = (unsigned)__builtin_amdgcn_cvt_pk_fp8_f32(
                    f.z, f.w, (int)v, true);
                u.d[m] = (int)v;
            }
            af[ks] = u.v;
        }
    }

    // B lane base: code bcol, dims h*32; per (kt,ks): +kt*32768 + ks*64.
    const unsigned char* wB = wb8 + (size_t)bcol * 256 + h * 32;

    unsigned s0[16], s1[16];
#pragma unroll
    for (int r = 0; r < 16; ++r) { s0[r] = 0xFFFFFFFFu; s1[r] = 0xFFFFFFFFu; }

    f32x16 acc;
    union Bu { uint4 q[2]; i32x8 v; };
    Bu a0, a1, a2, a3, n0, n1, n2, n3;

    // Interleaved half-batch prefetch: next tile's chunks issued between the
    // current tile's MFMA pairs (~340cy lead > L2 latency). Same B bytes and
    // same af0->af3 chain order per kt as verified R13 => bit-identical keys.
    LOADC(a0, 0, 0); LOADC(a1, 0, 1); LOADC(a2, 0, 2); LOADC(a3, 0, 3);

    for (int kt = 0; kt < 64; kt += 2) {
        INIT128(acc);
        __builtin_amdgcn_s_setprio(1);
        MFMA1(af[0], a0); MFMA1(af[1], a1);
        __builtin_amdgcn_s_setprio(0);
        LOADC(n0, kt + 1, 0); LOADC(n1, kt + 1, 1);
        __builtin_amdgcn_s_setprio(1);
        MFMA1(af[2], a2); MFMA1(af[3], a3);
        __builtin_amdgcn_s_setprio(0);
        LOADC(n2, kt + 1, 2); LOADC(n3, kt + 1, 3);
        SEL16(acc, kt);

        INIT128(acc);
        __builtin_amdgcn_s_setprio(1);
        MFMA1(af[0], n0); MFMA1(af[1], n1);
        __builtin_amdgcn_s_setprio(0);
        if (kt + 2 < 64) { LOADC(a0, kt + 2, 0); LOADC(a1, kt + 2, 1); }
        __builtin_amdgcn_s_setprio(1);
        MFMA1(af[2], n2); MFMA1(af[3], n3);
        __builtin_amdgcn_s_setprio(0);
        if (kt + 2 < 64) { LOADC(a2, kt + 2, 2); LOADC(a3, kt + 2, 3); }
        SEL16(acc, kt + 1);
    }

    // merge: 32 rows x 256 keys = 32 KB; per-thread writes disjoint
    for (int r = 0; r < 16; ++r) {
        int rloc = (r & 3) + 8 * (r >> 2) + 4 * h;
        *(uint2*)&ms[rloc * 256 + bcol * 2] = make_uint2(s0[r], s1[r]);
    }
    __syncthreads();
    if (tid < 32) {
        const uint4* rowk = (const uint4*)(ms + tid * 256);
        unsigned best[8];
#pragma unroll
        for (int i = 0; i < 8; ++i) best[i] = 0xFFFFFFFFu;
        for (int i = 0; i < 64; ++i) {
            uint4 qv = rowk[(i + tid) & 63];   // rotated: bank spread
            unsigned kk[4] = {qv.x, qv.y, qv.z, qv.w};
#pragma unroll
            for (int e = 0; e < 4; ++e) {
                unsigned key = kk[e];
                if (key < best[7]) {
                    best[7] = key;
#pragma unroll
                    for (int j = 7; j > 0; --j)
                        if (best[j] < best[j - 1]) {
                            unsigned t = best[j]; best[j] = best[j - 1]; best[j - 1] = t;
                        }
                }
            }
        }
        unsigned* out = cand + (size_t)(rowBase + tid) * 8;
#pragma unroll
        for (int i = 0; i < 8; ++i) out[i] = best[i];
    }
}

// ---------- exact rescore (fp32 chain, R3-verified) + inline numpy x2 ----------
__global__ __launch_bounds__(256) void vq_rescore_write(
    const float* __restrict__ x, const float* __restrict__ w,
    const float* __restrict__ wn, const unsigned* __restrict__ cand,
    float* __restrict__ outq, float* __restrict__ outi) {
    __shared__ int winners[32];
    const int tid = threadIdx.x;
    const int lr = tid >> 3, cc = tid & 7;
    const int row = blockIdx.x * 32 + lr;

    int k = (int)(cand[(size_t)row * 8 + cc] & 0x1FFFu);
    const float* xr = x + (size_t)row * DDIM;
    const float* wr = w + (size_t)k * DDIM;
    // dot: single fp32 fmaf chain d-ascending (BLAS-exact, R2/R3-verified)
    // x2: numpy pairwise (two halves, 8 stride-8 chains, exact nesting)
    float dot = 0.f;
    float half[2];
#pragma unroll
    for (int hh = 0; hh < 2; ++hh) {
        float r[8];
#pragma unroll
        for (int t = 0; t < 16; ++t) {
            const int d = hh * 128 + t * 8;
            float4 xa = *(const float4*)(xr + d);
            float4 xb = *(const float4*)(xr + d + 4);
            float4 wa = *(const float4*)(wr + d);
            float4 wb = *(const float4*)(wr + d + 4);
            dot = __fmaf_rn(xa.x, wa.x, dot); dot = __fmaf_rn(xa.y, wa.y, dot);
            dot = __fmaf_rn(xa.z, wa.z, dot); dot = __fmaf_rn(xa.w, wa.w, dot);
            dot = __fmaf_rn(xb.x, wb.x, dot); dot = __fmaf_rn(xb.y, wb.y, dot);
            dot = __fmaf_rn(xb.z, wb.z, dot); dot = __fmaf_rn(xb.w, wb.w, dot);
            if (t == 0) {
                r[0] = __fmul_rn(xa.x, xa.x); r[1] = __fmul_rn(xa.y, xa.y);
                r[2] = __fmul_rn(xa.z, xa.z); r[3] = __fmul_rn(xa.w, xa.w);
                r[4] = __fmul_rn(xb.x, xb.x); r[5] = __fmul_rn(xb.y, xb.y);
                r[6] = __fmul_rn(xb.z, xb.z); r[7] = __fmul_rn(xb.w, xb.w);
            } else {
                r[0] = __fadd_rn(r[0], __fmul_rn(xa.x, xa.x));
                r[1] = __fadd_rn(r[1], __fmul_rn(xa.y, xa.y));
                r[2] = __fadd_rn(r[2], __fmul_rn(xa.z, xa.z));
                r[3] = __fadd_rn(r[3], __fmul_rn(xa.w, xa.w));
                r[4] = __fadd_rn(r[4], __fmul_rn(xb.x, xb.x));
                r[5] = __fadd_rn(r[5], __fmul_rn(xb.y, xb.y));
                r[6] = __fadd_rn(r[6], __fmul_rn(xb.w == xb.w ? xb.z : xb.z, xb.z));
                r[7] = __fadd_rn(r[7], __fmul_rn(xb.w, xb.w));
            }
        }
        half[hh] = __fadd_rn(__fadd_rn(__fadd_rn(r[0], r[1]), __fadd_rn(r[2], r[3])),
                             __fadd_rn(__fadd_rn(r[4], r[5]), __fadd_rn(r[6], r[7])));
    }
    float x2v = __fadd_rn(half[0], half[1]);
    float dv = __fsub_rn(__fadd_rn(x2v, wn[k]), __fmul_rn(2.0f, dot));
    // lexicographic (dv,k) min across 8 candidate lanes (first-occurrence)
#pragma unroll
    for (int m = 1; m < 8; m <<= 1) {
        float od = __shfl_xor(dv, m, 64);
        int   ok = __shfl_xor(k,  m, 64);
        if (od < dv || (od == dv && ok < k)) { dv = od; k = ok; }
    }
    if (cc == 0) winners[lr] = k;
    __syncthreads();
    if (tid < 32) outi[blockIdx.x * 32 + tid] = (float)winners[tid];
    for (int u = tid; u < 32 * 64; u += 256) {
        int r = u >> 6, c4 = u & 63;
        *reinterpret_cast<float4*>(outq + (size_t)(blockIdx.x * 32 + r) * DDIM + c4 * 4) =
            *reinterpret_cast<const float4*>(w + (size_t)winners[r] * DDIM + c4 * 4);
    }
}

extern "C" void kernel_launch(void* const* d_in, const int* in_sizes, int n_in,
                              void* d_out, int out_size, void* d_ws, size_t ws_size,
                              hipStream_t stream) {
    const float* x = (const float*)d_in[0];
    const float* w = (const float*)d_in[1];
    const int N = in_sizes[0] / DDIM;   // 32768
    const int K = in_sizes[1] / DDIM;   // 8192
    float* outq = (float*)d_out;
    float* outi = outq + (size_t)N * DDIM;

    unsigned char* wb8 = (unsigned char*)d_ws;                // K*256 = 2 MB
    float* wn = (float*)(wb8 + (size_t)K * DDIM);             // K floats
    unsigned* cand = (unsigned*)(wn + K);                     // N*8 u32 = 1 MB

    hipLaunchKernelGGL(vq_prep_w, dim3(K / 32), dim3(256), 0, stream, w, wn, wb8);
    hipLaunchKernelGGL(vq_score, dim3(N / 32), dim3(256), 0, stream, x, wb8, cand);
    hipLaunchKernelGGL(vq_rescore_write, dim3(N / 32), dim3(256), 0, stream,
                       x, w, wn, cand, outq, outi);
}